// Round 2
// baseline (340.174 us; speedup 1.0000x reference)
//
#include <hip/hip_runtime.h>

// 2-layer LSTM (H=64) encode(128) + AR(60), B=4096, persistent per-block.
// grid=256 x 512 threads (8 waves = 2/SIMD). Waves w and w+4 duplicate the
// GEMMs (MFMA pipe is idle anyway) and split the epilogue by accumulator row
// half -> per-wave VALU halves, TLP doubles. A0/A1 double-buffered: 1 barrier
// per encode step, 3 per AR step. h-writes packed to b32 via shfl_xor.

#define T_ENC 128
#define D_IN 4
#define H 64
#define STEPS 60
#define M 16
#define A0S 104   // halves/row: [x(4) | h0(64) | zero-pad(28)] + 8 slack
#define A1S 136   // halves/row: [h0(64) | h1(64)] + 8 slack
#define NITER (T_ENC + STEPS)

typedef _Float16 half8 __attribute__((ext_vector_type(8)));
typedef float float4v __attribute__((ext_vector_type(4)));

__device__ __forceinline__ float fast_sigmoid(float x) {
    float e = __builtin_amdgcn_exp2f(-1.44269504f * x);
    return __builtin_amdgcn_rcpf(1.0f + e);
}
__device__ __forceinline__ float fast_tanh(float x) {
    float e = __builtin_amdgcn_exp2f(2.88539008f * x);   // exp(2x)
    return __builtin_fmaf(-2.0f, __builtin_amdgcn_rcpf(e + 1.0f), 1.0f);
}

__global__ __launch_bounds__(512, 2) void lstm_ar_kernel(
    const float* __restrict__ x,
    const float* __restrict__ Wih0, const float* __restrict__ Whh0,
    const float* __restrict__ bih0, const float* __restrict__ bhh0,
    const float* __restrict__ Wih1, const float* __restrict__ Whh1,
    const float* __restrict__ bih1, const float* __restrict__ bhh1,
    const float* __restrict__ Wfc,  const float* __restrict__ bfc,
    float* __restrict__ out)
{
    __shared__ __align__(16) _Float16 A0buf[2][M * A0S];
    __shared__ __align__(16) _Float16 A1buf[2][M * A1S];

    const int tid   = threadIdx.x;
    const int wave  = tid >> 6;
    const int lane  = tid & 63;
    const int n16   = lane & 15;
    const int quad  = lane >> 4;
    const int w4    = wave & 3;        // column-group / tau base (waves w, w+4 identical)
    const int rbase = (wave >> 2) * 2; // epilogue row-half split
    const int m0    = blockIdx.x * M;

    _Float16* A0f = &A0buf[0][0];
    _Float16* A1f = &A1buf[0][0];
    for (int i = tid; i < 2 * M * A0S; i += 512) A0f[i] = (_Float16)0.f;
    for (int i = tid; i < 2 * M * A1S; i += 512) A1f[i] = (_Float16)0.f;

    // ---- weight B-fragments (fp16): B[k][n], n = 16*(w4 + 4*tau) + n16 ----
    half8 B0f[3][4];
    half8 B1f[4][4];
    half8 Bfc[2];
    float b0v[4], b1v[4];
    #pragma unroll
    for (int tau = 0; tau < 4; ++tau) {
        const int n = 16 * (w4 + 4 * tau) + n16;
        b0v[tau] = bih0[n] + bhh0[n];
        b1v[tau] = bih1[n] + bhh1[n];
        #pragma unroll
        for (int kt = 0; kt < 3; ++kt) {
            #pragma unroll
            for (int j = 0; j < 8; ++j) {
                const int k = kt * 32 + quad * 8 + j;
                float v = 0.f;
                if (k < 4)       v = Wih0[n * D_IN + k];
                else if (k < 68) v = Whh0[n * H + (k - 4)];
                B0f[kt][tau][j] = (_Float16)v;
            }
        }
        #pragma unroll
        for (int kt = 0; kt < 4; ++kt) {
            #pragma unroll
            for (int j = 0; j < 8; ++j) {
                const int k = kt * 32 + quad * 8 + j;
                const float v = (k < H) ? Wih1[n * H + k] : Whh1[n * H + (k - H)];
                B1f[kt][tau][j] = (_Float16)v;
            }
        }
    }
    // head matvec as MFMA: B[k][d] = Wfc[d][k] for d = n16 < 4
    #pragma unroll
    for (int kt = 0; kt < 2; ++kt)
        #pragma unroll
        for (int j = 0; j < 8; ++j) {
            const int k = kt * 32 + quad * 8 + j;
            Bfc[kt][j] = (_Float16)((n16 < 4) ? Wfc[n16 * H + k] : 0.f);
        }
    const float bfcv = (n16 < 4) ? bfc[n16] : 0.f;

    float c0s[2] = {0.f, 0.f};
    float c1s[2] = {0.f, 0.f};

    __syncthreads();                 // zeroing done
    if (wave == 1) {                 // load x_0 into buffer 0
        const int me = lane >> 2, d = lane & 3;
        A0buf[0][me * A0S + d] = (_Float16)x[(size_t)(m0 + me) * T_ENC * D_IN + d];
    }
    __syncthreads();                 // x_0 visible

    const int m    = n16;            // A-fragment row (batch element) for this lane
    const int jcol = 16 * w4 + n16;  // hidden column this lane owns in epilogues

    for (int t = 0; t < NITER; ++t) {
        const int p = t & 1;

        // ---- GEMM0: gates0 = [x(t); h0(t-1)] @ W0^T  (bias in C-init) ----
        float4v C0[4];
        #pragma unroll
        for (int tau = 0; tau < 4; ++tau)
            C0[tau] = (float4v){b0v[tau], b0v[tau], b0v[tau], b0v[tau]};
        half8 a0[3];
        #pragma unroll
        for (int kt = 0; kt < 3; ++kt)
            a0[kt] = *(const half8*)&A0buf[p][m * A0S + kt * 32 + quad * 8];
        #pragma unroll
        for (int kt = 0; kt < 3; ++kt)
            #pragma unroll
            for (int tau = 0; tau < 4; ++tau)
                C0[tau] = __builtin_amdgcn_mfma_f32_16x16x32_f16(
                    a0[kt], B0f[kt][tau], C0[tau], 0, 0, 0);

        // x prefetch into the other buffer (encode phase)
        if (t < T_ENC && wave == 1) {
            const int me = lane >> 2, d = lane & 3;
            const int tn = (t + 1 < T_ENC) ? t + 1 : T_ENC - 1;
            A0buf[1 - p][me * A0S + d] =
                (_Float16)x[(size_t)(m0 + me) * T_ENC * D_IN + tn * D_IN + d];
        }

        // ---- epilogue 0 (row-half split; packed b32 h-writes) ----
        #pragma unroll
        for (int rr = 0; rr < 2; ++rr) {
            const int r   = rbase + rr;
            const int row = quad * 4 + r;
            const float ig = fast_sigmoid(C0[0][r]);
            const float fg = fast_sigmoid(C0[1][r]);
            const float gg = fast_tanh   (C0[2][r]);
            const float og = fast_sigmoid(C0[3][r]);
            const float c  = fg * c0s[rr] + ig * gg;
            c0s[rr] = c;
            const float h  = og * fast_tanh(c);
            const float hn = __shfl_xor(h, 1);
            if ((lane & 1) == 0) {   // jcol even: pack (jcol, jcol+1) into one dword
                union { _Float16 h2[2]; unsigned u; } pk;
                pk.h2[0] = (_Float16)h;
                pk.h2[1] = (_Float16)hn;
                *(unsigned*)&A1buf[p][row * A1S + jcol]         = pk.u; // layer1 input
                *(unsigned*)&A0buf[1 - p][row * A0S + 4 + jcol] = pk.u; // next-step layer0 input
            }
        }
        __syncthreads();   // B_mid: h0(t) visible; A0[1-p]/A1[1-p] safe to write after

        // ---- GEMM1: gates1 = [h0(t); h1(t-1)] @ W1^T ----
        float4v C1[4];
        #pragma unroll
        for (int tau = 0; tau < 4; ++tau)
            C1[tau] = (float4v){b1v[tau], b1v[tau], b1v[tau], b1v[tau]};
        half8 a1[4];
        #pragma unroll
        for (int kt = 0; kt < 4; ++kt)
            a1[kt] = *(const half8*)&A1buf[p][m * A1S + kt * 32 + quad * 8];
        #pragma unroll
        for (int kt = 0; kt < 4; ++kt)
            #pragma unroll
            for (int tau = 0; tau < 4; ++tau)
                C1[tau] = __builtin_amdgcn_mfma_f32_16x16x32_f16(
                    a1[kt], B1f[kt][tau], C1[tau], 0, 0, 0);

        // ---- epilogue 1 ----
        #pragma unroll
        for (int rr = 0; rr < 2; ++rr) {
            const int r   = rbase + rr;
            const int row = quad * 4 + r;
            const float ig = fast_sigmoid(C1[0][r]);
            const float fg = fast_sigmoid(C1[1][r]);
            const float gg = fast_tanh   (C1[2][r]);
            const float og = fast_sigmoid(C1[3][r]);
            const float c  = fg * c1s[rr] + ig * gg;
            c1s[rr] = c;
            const float h  = og * fast_tanh(c);
            const float hn = __shfl_xor(h, 1);
            if ((lane & 1) == 0) {
                union { _Float16 h2[2]; unsigned u; } pk;
                pk.h2[0] = (_Float16)h;
                pk.h2[1] = (_Float16)hn;
                *(unsigned*)&A1buf[1 - p][row * A1S + H + jcol] = pk.u; // h1 for next step
            }
        }

        // ---- AR head: pred = h1 @ Wfc^T + bfc  (2-MFMA matvec on wave 0) ----
        if (t >= T_ENC) {
            __syncthreads();   // h1(t) visible
            if (wave == 0) {
                half8 af[2];
                #pragma unroll
                for (int kt = 0; kt < 2; ++kt)
                    af[kt] = *(const half8*)&A1buf[1 - p][m * A1S + H + kt * 32 + quad * 8];
                float4v Cp = (float4v){bfcv, bfcv, bfcv, bfcv};
                Cp = __builtin_amdgcn_mfma_f32_16x16x32_f16(af[0], Bfc[0], Cp, 0, 0, 0);
                Cp = __builtin_amdgcn_mfma_f32_16x16x32_f16(af[1], Bfc[1], Cp, 0, 0, 0);
                if (n16 < 4) {
                    const int s = t - T_ENC;
                    #pragma unroll
                    for (int r = 0; r < 4; ++r) {
                        const int row = quad * 4 + r;
                        out[((size_t)(m0 + row) * STEPS + s) * D_IN + n16] = Cp[r];
                        A0buf[1 - p][row * A0S + n16] = (_Float16)Cp[r]; // next x input
                    }
                }
            }
            __syncthreads();   // pred visible for GEMM0(t+1)
        }
    }
}

extern "C" void kernel_launch(void* const* d_in, const int* in_sizes, int n_in,
                              void* d_out, int out_size, void* d_ws, size_t ws_size,
                              hipStream_t stream) {
    const float* x    = (const float*)d_in[0];
    const float* Wih0 = (const float*)d_in[1];
    const float* Whh0 = (const float*)d_in[2];
    const float* bih0 = (const float*)d_in[3];
    const float* bhh0 = (const float*)d_in[4];
    const float* Wih1 = (const float*)d_in[5];
    const float* Whh1 = (const float*)d_in[6];
    const float* bih1 = (const float*)d_in[7];
    const float* bhh1 = (const float*)d_in[8];
    const float* Wfc  = (const float*)d_in[9];
    const float* bfc  = (const float*)d_in[10];
    float* out = (float*)d_out;

    dim3 grid(4096 / M);   // 256 blocks, one per CU
    dim3 block(512);       // 8 waves = 2 per SIMD
    lstm_ar_kernel<<<grid, block, 0, stream>>>(
        x, Wih0, Whh0, bih0, bhh0, Wih1, Whh1, bih1, bhh1, Wfc, bfc, out);
}

// Round 3
// 308.197 us; speedup vs baseline: 1.1038x; 1.1038x over previous
//
#include <hip/hip_runtime.h>

// 2-layer LSTM (H=64) encode(128) + AR(60), B=4096, persistent per-block.
// grid=256 x 256 threads (4 waves, 1/SIMD). Staggered retiming:
//   encode iter t computes layer1(t) AND layer0(t+1) concurrently -> 1 barrier.
//   AR: layer0 fused as [h0|h1]·[Whh0 | Wih0@Wfc] (pred off critical path) -> 2 barriers.
// Weights in registers as fp16 MFMA B-fragments; preds buffered in LDS, bulk store at end.

#define T_ENC 128
#define D_IN 4
#define H 64
#define STEPS 60
#define M 16
#define A0S 104   // halves/row: [x(4) | h0(64) | zero-pad] ; 52 dwords
#define A1S 136   // halves/row: [h0(64) | h1(64)] + slack  ; 68 dwords

typedef _Float16 half8 __attribute__((ext_vector_type(8)));
typedef _Float16 half4_t __attribute__((ext_vector_type(4)));
typedef float float4v __attribute__((ext_vector_type(4)));

__device__ __forceinline__ float fast_sigmoid(float x) {
    float e = __builtin_amdgcn_exp2f(-1.44269504f * x);
    return __builtin_amdgcn_rcpf(1.0f + e);
}
__device__ __forceinline__ float fast_tanh(float x) {
    float e = __builtin_amdgcn_exp2f(2.88539008f * x);   // exp(2x)
    return __builtin_fmaf(-2.0f, __builtin_amdgcn_rcpf(e + 1.0f), 1.0f);
}

__global__ __launch_bounds__(256, 1) void lstm_ar_kernel(
    const float* __restrict__ x,
    const float* __restrict__ Wih0, const float* __restrict__ Whh0,
    const float* __restrict__ bih0, const float* __restrict__ bhh0,
    const float* __restrict__ Wih1, const float* __restrict__ Whh1,
    const float* __restrict__ bih1, const float* __restrict__ bhh1,
    const float* __restrict__ Wfc,  const float* __restrict__ bfc,
    float* __restrict__ out)
{
    __shared__ __align__(16) _Float16 A0buf[2][M * A0S];
    __shared__ __align__(16) _Float16 A1buf[2][M * A1S];
    __shared__ __align__(16) float    xstash[2][512];       // [buf][elem*32 + st*4 + d]
    __shared__ __align__(16) float    predsS[M * STEPS * D_IN];

    const int tid  = threadIdx.x;
    const int wave = tid >> 6;
    const int lane = tid & 63;
    const int n16  = lane & 15;
    const int quad = lane >> 4;
    const int m0   = blockIdx.x * M;
    const int m    = n16;             // A-frag row (batch element)
    const int jcol = 16 * wave + n16; // hidden column owned in epilogues

    { _Float16* z = &A0buf[0][0]; for (int i = tid; i < 2 * M * A0S; i += 256) z[i] = (_Float16)0.f; }
    { _Float16* z = &A1buf[0][0]; for (int i = tid; i < 2 * M * A1S; i += 256) z[i] = (_Float16)0.f; }

    // ---- weight B-fragments (fp16): B[k][n], n = 16*(wave + 4*tau) + n16 ----
    half8 B0f[3][4];    // encode layer0: K=96, [x(4); h0(64); 0pad]
    half8 B1f[4][4];    // layer1: K=128, [h0; h1]
    half8 B0ar[4][4];   // AR layer0: K=128, [Whh0 | Wx=Wih0@Wfc]
    half8 Bfc[2];       // head (wave0 only)
    float b0v[4], b1v[4], b0ar[4];
    #pragma unroll
    for (int tau = 0; tau < 4; ++tau) {
        const int n = 16 * (wave + 4 * tau) + n16;
        b0v[tau] = bih0[n] + bhh0[n];
        b1v[tau] = bih1[n] + bhh1[n];
        float wb = 0.f;
        #pragma unroll
        for (int d = 0; d < 4; ++d) wb += Wih0[n * D_IN + d] * bfc[d];
        b0ar[tau] = b0v[tau] + wb;
        #pragma unroll
        for (int kt = 0; kt < 3; ++kt)
            #pragma unroll
            for (int j = 0; j < 8; ++j) {
                const int k = kt * 32 + quad * 8 + j;
                float v = 0.f;
                if (k < 4)       v = Wih0[n * D_IN + k];
                else if (k < 68) v = Whh0[n * H + (k - 4)];
                B0f[kt][tau][j] = (_Float16)v;
            }
        #pragma unroll
        for (int kt = 0; kt < 4; ++kt)
            #pragma unroll
            for (int j = 0; j < 8; ++j) {
                const int k = kt * 32 + quad * 8 + j;
                const float v = (k < H) ? Wih1[n * H + k] : Whh1[n * H + (k - H)];
                B1f[kt][tau][j] = (_Float16)v;
            }
        #pragma unroll
        for (int kt = 0; kt < 4; ++kt)
            #pragma unroll
            for (int j = 0; j < 8; ++j) {
                const int k = kt * 32 + quad * 8 + j;
                float v;
                if (k < H) v = Whh0[n * H + k];
                else {
                    const int c = k - H;
                    v = Wih0[n * D_IN + 0] * Wfc[0 * H + c] + Wih0[n * D_IN + 1] * Wfc[1 * H + c]
                      + Wih0[n * D_IN + 2] * Wfc[2 * H + c] + Wih0[n * D_IN + 3] * Wfc[3 * H + c];
                }
                B0ar[kt][tau][j] = (_Float16)v;
            }
    }
    float bfcv = 0.f;
    if (wave == 0) {
        #pragma unroll
        for (int kt = 0; kt < 2; ++kt)
            #pragma unroll
            for (int j = 0; j < 8; ++j) {
                const int k = kt * 32 + quad * 8 + j;
                Bfc[kt][j] = (_Float16)((n16 < 4) ? Wfc[n16 * H + k] : 0.f);
            }
        if (n16 < 4) bfcv = bfc[n16];
    }

    float c0s[4] = {0.f, 0.f, 0.f, 0.f};
    float c1s[4] = {0.f, 0.f, 0.f, 0.f};

    __syncthreads();   // LDS zeroing done

    // ---- prologue: tranche0 -> stash[0]; x(0)->A0buf[1], x(1)->A0buf[0] ----
    if (wave == 2) {
        const int elem = lane >> 2, st2 = (lane & 3) * 2;
        const float4v xa = *(const float4v*)&x[((size_t)(m0 + elem) * T_ENC + st2) * 4];
        const float4v xb = *(const float4v*)&x[((size_t)(m0 + elem) * T_ENC + st2 + 1) * 4];
        *(float4v*)&xstash[0][elem * 32 + st2 * 4]       = xa;
        *(float4v*)&xstash[0][elem * 32 + (st2 + 1) * 4] = xb;
    }
    __syncthreads();
    if (wave == 2 && lane < 16) {
        const float4v v0 = *(const float4v*)&xstash[0][lane * 32 + 0];
        const float4v v1 = *(const float4v*)&xstash[0][lane * 32 + 4];
        *(half4_t*)&A0buf[1][lane * A0S] =
            (half4_t){(_Float16)v0[0], (_Float16)v0[1], (_Float16)v0[2], (_Float16)v0[3]};
        *(half4_t*)&A0buf[0][lane * A0S] =
            (half4_t){(_Float16)v1[0], (_Float16)v1[1], (_Float16)v1[2], (_Float16)v1[3]};
    }
    __syncthreads();

    // ---- prologue layer0 step 0: GEMM0 over A0buf[1] = [x(0) | 0] ----
    {
        half8 a0f[3];
        #pragma unroll
        for (int kt = 0; kt < 3; ++kt)
            a0f[kt] = *(const half8*)&A0buf[1][m * A0S + kt * 32 + quad * 8];
        float4v C0[4];
        #pragma unroll
        for (int tau = 0; tau < 4; ++tau)
            C0[tau] = (float4v){b0v[tau], b0v[tau], b0v[tau], b0v[tau]};
        #pragma unroll
        for (int kt = 0; kt < 3; ++kt)
            #pragma unroll
            for (int tau = 0; tau < 4; ++tau)
                C0[tau] = __builtin_amdgcn_mfma_f32_16x16x32_f16(a0f[kt], B0f[kt][tau], C0[tau], 0, 0, 0);
        #pragma unroll
        for (int r = 0; r < 4; ++r) {
            const float ig = fast_sigmoid(C0[0][r]);
            const float fg = fast_sigmoid(C0[1][r]);
            const float gg = fast_tanh   (C0[2][r]);
            const float og = fast_sigmoid(C0[3][r]);
            const float c  = fg * c0s[r] + ig * gg;
            c0s[r] = c;
            const _Float16 hh = (_Float16)(og * fast_tanh(c));
            const int row = quad * 4 + r;
            A1buf[0][row * A1S + jcol]     = hh;
            A0buf[0][row * A0S + 4 + jcol] = hh;
        }
    }
    __syncthreads();

    float4v xpa, xpb;   // in-flight x tranche (wave2)

    // ---- encode: iter t computes layer1(t) and layer0(t+1); 1 barrier/iter ----
    for (int t = 0; t < T_ENC; ++t) {
        const int p = t & 1;
        const _Float16* cur0 = &A0buf[p][0];
        const _Float16* cur1 = &A1buf[p][0];
        _Float16* nxt0 = &A0buf[1 - p][0];
        _Float16* nxt1 = &A1buf[1 - p][0];

        // x tranche pipeline: load at t%8==0, stash at t%8==4
        if (wave == 2) {
            if ((t & 7) == 0) {
                const int k = (t >> 3) + 1;
                const int elem = lane >> 2, st2 = (lane & 3) * 2;
                int t1 = 8 * k + st2;     if (t1 > 127) t1 = 127;
                int t2 = 8 * k + st2 + 1; if (t2 > 127) t2 = 127;
                xpa = *(const float4v*)&x[((size_t)(m0 + elem) * T_ENC + t1) * 4];
                xpb = *(const float4v*)&x[((size_t)(m0 + elem) * T_ENC + t2) * 4];
            }
            if ((t & 7) == 4) {
                const int bf = ((t >> 3) + 1) & 1;
                const int elem = lane >> 2, st2 = (lane & 3) * 2;
                *(float4v*)&xstash[bf][elem * 32 + st2 * 4]       = xpa;
                *(float4v*)&xstash[bf][elem * 32 + (st2 + 1) * 4] = xpb;
            }
        }

        half8 a1f[4], a0f[3];
        #pragma unroll
        for (int kt = 0; kt < 4; ++kt)
            a1f[kt] = *(const half8*)&cur1[m * A1S + kt * 32 + quad * 8];
        #pragma unroll
        for (int kt = 0; kt < 3; ++kt)
            a0f[kt] = *(const half8*)&cur0[m * A0S + kt * 32 + quad * 8];

        float4v C1[4], C0[4];
        #pragma unroll
        for (int tau = 0; tau < 4; ++tau) {
            C1[tau] = (float4v){b1v[tau], b1v[tau], b1v[tau], b1v[tau]};
            C0[tau] = (float4v){b0v[tau], b0v[tau], b0v[tau], b0v[tau]};
        }
        #pragma unroll
        for (int kt = 0; kt < 4; ++kt)
            #pragma unroll
            for (int tau = 0; tau < 4; ++tau)
                C1[tau] = __builtin_amdgcn_mfma_f32_16x16x32_f16(a1f[kt], B1f[kt][tau], C1[tau], 0, 0, 0);
        #pragma unroll
        for (int kt = 0; kt < 3; ++kt)
            #pragma unroll
            for (int tau = 0; tau < 4; ++tau)
                C0[tau] = __builtin_amdgcn_mfma_f32_16x16x32_f16(a0f[kt], B0f[kt][tau], C0[tau], 0, 0, 0);

        // epi1: layer1(t) -> h1(t)
        #pragma unroll
        for (int r = 0; r < 4; ++r) {
            const float ig = fast_sigmoid(C1[0][r]);
            const float fg = fast_sigmoid(C1[1][r]);
            const float gg = fast_tanh   (C1[2][r]);
            const float og = fast_sigmoid(C1[3][r]);
            const float c  = fg * c1s[r] + ig * gg;
            c1s[r] = c;
            const int row = quad * 4 + r;
            nxt1[row * A1S + 64 + jcol] = (_Float16)(og * fast_tanh(c));
        }
        // epi0: layer0(t+1) -> h0(t+1)
        #pragma unroll
        for (int r = 0; r < 4; ++r) {
            const float ig = fast_sigmoid(C0[0][r]);
            const float fg = fast_sigmoid(C0[1][r]);
            const float gg = fast_tanh   (C0[2][r]);
            const float og = fast_sigmoid(C0[3][r]);
            const float c  = fg * c0s[r] + ig * gg;
            c0s[r] = c;
            const _Float16 hh = (_Float16)(og * fast_tanh(c));
            const int row = quad * 4 + r;
            nxt1[row * A1S + jcol]     = hh;
            nxt0[row * A0S + 4 + jcol] = hh;
        }
        // x(t+2) -> nxt0 x-slot
        if (wave == 2 && lane < 16) {
            const int st = (t + 2) & 7, bf = ((t + 2) >> 3) & 1;
            const float4v v = *(const float4v*)&xstash[bf][lane * 32 + st * 4];
            *(half4_t*)&nxt0[lane * A0S] =
                (half4_t){(_Float16)v[0], (_Float16)v[1], (_Float16)v[2], (_Float16)v[3]};
        }
        __syncthreads();
    }

    // ---- AR: 2 barriers/step; pred off critical path via fused Wx ----
    for (int s = 0; s < STEPS; ++s) {
        const int q = s & 1;
        const _Float16* cur = &A1buf[q][0];
        _Float16* nxt = &A1buf[1 - q][0];

        half8 a1f[4];
        #pragma unroll
        for (int kt = 0; kt < 4; ++kt)
            a1f[kt] = *(const half8*)&cur[m * A1S + kt * 32 + quad * 8];
        float4v C1[4];
        #pragma unroll
        for (int tau = 0; tau < 4; ++tau)
            C1[tau] = (float4v){b1v[tau], b1v[tau], b1v[tau], b1v[tau]};
        #pragma unroll
        for (int kt = 0; kt < 4; ++kt)
            #pragma unroll
            for (int tau = 0; tau < 4; ++tau)
                C1[tau] = __builtin_amdgcn_mfma_f32_16x16x32_f16(a1f[kt], B1f[kt][tau], C1[tau], 0, 0, 0);
        #pragma unroll
        for (int r = 0; r < 4; ++r) {
            const float ig = fast_sigmoid(C1[0][r]);
            const float fg = fast_sigmoid(C1[1][r]);
            const float gg = fast_tanh   (C1[2][r]);
            const float og = fast_sigmoid(C1[3][r]);
            const float c  = fg * c1s[r] + ig * gg;
            c1s[r] = c;
            const int row = quad * 4 + r;
            nxt[row * A1S + 64 + jcol] = (_Float16)(og * fast_tanh(c));
        }
        __syncthreads();   // B1: h1(s) visible

        half8 aA[4];
        #pragma unroll
        for (int kt = 0; kt < 2; ++kt)
            aA[kt] = *(const half8*)&cur[m * A1S + kt * 32 + quad * 8];          // h0(s)
        #pragma unroll
        for (int kt = 2; kt < 4; ++kt)
            aA[kt] = *(const half8*)&nxt[m * A1S + 64 + (kt - 2) * 32 + quad * 8]; // h1(s)
        float4v C0[4];
        #pragma unroll
        for (int tau = 0; tau < 4; ++tau)
            C0[tau] = (float4v){b0ar[tau], b0ar[tau], b0ar[tau], b0ar[tau]};
        #pragma unroll
        for (int kt = 0; kt < 4; ++kt)
            #pragma unroll
            for (int tau = 0; tau < 4; ++tau)
                C0[tau] = __builtin_amdgcn_mfma_f32_16x16x32_f16(aA[kt], B0ar[kt][tau], C0[tau], 0, 0, 0);

        if (wave == 0) {   // head: pred(s) = Wfc·h1(s)+bfc — output only, off critical path
            float4v Cp = (float4v){bfcv, bfcv, bfcv, bfcv};
            Cp = __builtin_amdgcn_mfma_f32_16x16x32_f16(aA[2], Bfc[0], Cp, 0, 0, 0);
            Cp = __builtin_amdgcn_mfma_f32_16x16x32_f16(aA[3], Bfc[1], Cp, 0, 0, 0);
            if (n16 < 4) {
                #pragma unroll
                for (int r = 0; r < 4; ++r)
                    predsS[(quad * 4 + r) * (STEPS * D_IN) + s * 4 + n16] = Cp[r];
            }
        }

        #pragma unroll
        for (int r = 0; r < 4; ++r) {
            const float ig = fast_sigmoid(C0[0][r]);
            const float fg = fast_sigmoid(C0[1][r]);
            const float gg = fast_tanh   (C0[2][r]);
            const float og = fast_sigmoid(C0[3][r]);
            const float c  = fg * c0s[r] + ig * gg;
            c0s[r] = c;
            const int row = quad * 4 + r;
            nxt[row * A1S + jcol] = (_Float16)(og * fast_tanh(c));
        }
        __syncthreads();   // B2
    }

    // ---- bulk store preds ----
    for (int j = tid; j < M * STEPS; j += 256) {      // 960 float4
        const int elem = j / STEPS, r = j - elem * STEPS;
        ((float4v*)out)[(size_t)(m0 + elem) * STEPS + r] = ((const float4v*)predsS)[j];
    }
}

extern "C" void kernel_launch(void* const* d_in, const int* in_sizes, int n_in,
                              void* d_out, int out_size, void* d_ws, size_t ws_size,
                              hipStream_t stream) {
    const float* x    = (const float*)d_in[0];
    const float* Wih0 = (const float*)d_in[1];
    const float* Whh0 = (const float*)d_in[2];
    const float* bih0 = (const float*)d_in[3];
    const float* bhh0 = (const float*)d_in[4];
    const float* Wih1 = (const float*)d_in[5];
    const float* Whh1 = (const float*)d_in[6];
    const float* bih1 = (const float*)d_in[7];
    const float* bhh1 = (const float*)d_in[8];
    const float* Wfc  = (const float*)d_in[9];
    const float* bfc  = (const float*)d_in[10];
    float* out = (float*)d_out;

    dim3 grid(4096 / M);   // 256 blocks, one per CU
    dim3 block(256);       // 4 waves, 1 per SIMD
    lstm_ar_kernel<<<grid, block, 0, stream>>>(
        x, Wih0, Whh0, bih0, bhh0, Wih1, Whh1, bih1, bhh1, Wfc, bfc, out);
}

// Round 4
// 261.809 us; speedup vs baseline: 1.2993x; 1.1772x over previous
//
#include <hip/hip_runtime.h>

// 2-layer LSTM (H=64) encode(128) + AR(60), B=4096, persistent per-block.
// 256 blocks x 512 threads (8 waves = 2/SIMD). Wave specialization:
//   waves 0-3 (grp0) own layer 1 (c1, B1f); waves 4-7 (grp1) own layer 0
//   (c0, B0f encode / B0ar AR / Bfc head). Wave w and w+4 share a SIMD ->
//   two independent GEMM+epilogue chains per SIMD, no duplicated work.
// Encode: 1 barrier/step. AR: 2 barriers/step, cross-phase MFMA pre-compute.
// x converted to fp16 LDS once -> no global loads in the main loop.

#define T_ENC 128
#define D_IN 4
#define H 64
#define STEPS 60
#define M 16
#define A0S 104   // halves/row: [x(4) | h0(64) | zero-pad]
#define A1S 136   // halves/row: [h0(64) | h1(64)] + slack
#define XN (M * T_ENC * D_IN)   // 8192 halves

typedef _Float16 half8 __attribute__((ext_vector_type(8)));
typedef _Float16 half4_t __attribute__((ext_vector_type(4)));
typedef float float4v __attribute__((ext_vector_type(4)));

__device__ __forceinline__ float fast_sigmoid(float x) {
    float e = __builtin_amdgcn_exp2f(-1.44269504f * x);
    return __builtin_amdgcn_rcpf(1.0f + e);
}
__device__ __forceinline__ float fast_tanh(float x) {
    float e = __builtin_amdgcn_exp2f(2.88539008f * x);   // exp(2x)
    return __builtin_fmaf(-2.0f, __builtin_amdgcn_rcpf(e + 1.0f), 1.0f);
}

__global__ __launch_bounds__(512, 2) void lstm_ar_kernel(
    const float* __restrict__ x,
    const float* __restrict__ Wih0, const float* __restrict__ Whh0,
    const float* __restrict__ bih0, const float* __restrict__ bhh0,
    const float* __restrict__ Wih1, const float* __restrict__ Whh1,
    const float* __restrict__ bih1, const float* __restrict__ bhh1,
    const float* __restrict__ Wfc,  const float* __restrict__ bfc,
    float* __restrict__ out)
{
    __shared__ __align__(16) _Float16 A0buf[2][M * A0S];
    __shared__ __align__(16) _Float16 A1buf[2][M * A1S];
    __shared__ __align__(16) _Float16 xAll[XN];                // [elem][t][d] fp16
    __shared__ __align__(16) float    predsS[M * STEPS * D_IN];

    const int tid  = threadIdx.x;
    const int wave = tid >> 6;
    const int lane = tid & 63;
    const int n16  = lane & 15;
    const int quad = lane >> 4;
    const int grp  = wave >> 2;        // 0: layer-1 group, 1: layer-0 group
    const int w4   = wave & 3;
    const int m0   = blockIdx.x * M;
    const int m    = n16;              // A-frag row (batch element)
    const int jcol = 16 * w4 + n16;    // hidden column owned in epilogues

    { _Float16* z = &A0buf[0][0]; for (int i = tid; i < 2 * M * A0S; i += 512) z[i] = (_Float16)0.f; }
    { _Float16* z = &A1buf[0][0]; for (int i = tid; i < 2 * M * A1S; i += 512) z[i] = (_Float16)0.f; }
    // x -> fp16 LDS (one-time; removes all global loads from the main loop)
    for (int j = tid; j < XN / 4; j += 512) {
        const float4v v = *(const float4v*)&x[(size_t)m0 * T_ENC * D_IN + (size_t)j * 4];
        *(half4_t*)&xAll[j * 4] =
            (half4_t){(_Float16)v[0], (_Float16)v[1], (_Float16)v[2], (_Float16)v[3]};
    }

    // ---- per-group weight fragments: B[k][n], n = 16*(w4 + 4*tau) + n16, tau = gate ----
    half8 B1f[4][4];             // grp0: layer1, K=128 = [h0 | h1]
    half8 B0f[3][4];             // grp1: encode layer0, K=96 = [x(4); h0(64); pad]
    float b1v[4], b0v[4], b0arv[4];
    if (grp == 0) {
        #pragma unroll
        for (int tau = 0; tau < 4; ++tau) {
            const int n = 16 * (w4 + 4 * tau) + n16;
            b1v[tau] = bih1[n] + bhh1[n];
            #pragma unroll
            for (int kt = 0; kt < 4; ++kt)
                #pragma unroll
                for (int j = 0; j < 8; ++j) {
                    const int k = kt * 32 + quad * 8 + j;
                    B1f[kt][tau][j] = (_Float16)((k < H) ? Wih1[n * H + k] : Whh1[n * H + (k - H)]);
                }
        }
    } else {
        #pragma unroll
        for (int tau = 0; tau < 4; ++tau) {
            const int n = 16 * (w4 + 4 * tau) + n16;
            b0v[tau] = bih0[n] + bhh0[n];
            float wb = 0.f;
            #pragma unroll
            for (int d = 0; d < 4; ++d) wb += Wih0[n * D_IN + d] * bfc[d];
            b0arv[tau] = b0v[tau] + wb;
            #pragma unroll
            for (int kt = 0; kt < 3; ++kt)
                #pragma unroll
                for (int j = 0; j < 8; ++j) {
                    const int k = kt * 32 + quad * 8 + j;
                    float v = 0.f;
                    if (k < 4)       v = Wih0[n * D_IN + k];
                    else if (k < 68) v = Whh0[n * H + (k - 4)];
                    B0f[kt][tau][j] = (_Float16)v;
                }
        }
    }

    float c0s[4] = {0.f, 0.f, 0.f, 0.f};   // grp1 state
    float c1s[4] = {0.f, 0.f, 0.f, 0.f};   // grp0 state

    __syncthreads();   // LDS zero + xAll ready

    // x(0) -> A0buf[1] x-slot (prologue input); x(1) -> A0buf[0] (iter-0 input)
    if (grp == 1 && w4 == 2 && lane < 16) {
        *(half4_t*)&A0buf[1][lane * A0S] = *(const half4_t*)&xAll[(lane * T_ENC + 0) * D_IN];
        *(half4_t*)&A0buf[0][lane * A0S] = *(const half4_t*)&xAll[(lane * T_ENC + 1) * D_IN];
    }
    __syncthreads();

    // ---- prologue: L0 step 0 (grp1 only) ----
    if (grp == 1) {
        half8 a0f[3];
        #pragma unroll
        for (int kt = 0; kt < 3; ++kt)
            a0f[kt] = *(const half8*)&A0buf[1][m * A0S + kt * 32 + quad * 8];
        float4v C0[4];
        #pragma unroll
        for (int tau = 0; tau < 4; ++tau)
            C0[tau] = (float4v){b0v[tau], b0v[tau], b0v[tau], b0v[tau]};
        #pragma unroll
        for (int kt = 0; kt < 3; ++kt)
            #pragma unroll
            for (int tau = 0; tau < 4; ++tau)
                C0[tau] = __builtin_amdgcn_mfma_f32_16x16x32_f16(a0f[kt], B0f[kt][tau], C0[tau], 0, 0, 0);
        #pragma unroll
        for (int r = 0; r < 4; ++r) {
            const float ig = fast_sigmoid(C0[0][r]);
            const float fg = fast_sigmoid(C0[1][r]);
            const float gg = fast_tanh   (C0[2][r]);
            const float og = fast_sigmoid(C0[3][r]);
            const float c  = fg * c0s[r] + ig * gg;
            c0s[r] = c;
            const _Float16 hh = (_Float16)(og * fast_tanh(c));
            const int row = quad * 4 + r;
            A1buf[0][row * A1S + jcol]     = hh;
            A0buf[0][row * A0S + 4 + jcol] = hh;
        }
    }
    __syncthreads();

    // ---- encode: iter t = L1(t) on grp0  ||  L0(t+1) on grp1; 1 barrier ----
    for (int t = 0; t < T_ENC; ++t) {
        const int p = t & 1;
        if (grp == 0) {
            const _Float16* cur1 = &A1buf[p][0];
            _Float16* nxt1 = &A1buf[1 - p][0];
            half8 a1f[4];
            #pragma unroll
            for (int kt = 0; kt < 4; ++kt)
                a1f[kt] = *(const half8*)&cur1[m * A1S + kt * 32 + quad * 8];
            float4v C1[4];
            #pragma unroll
            for (int tau = 0; tau < 4; ++tau)
                C1[tau] = (float4v){b1v[tau], b1v[tau], b1v[tau], b1v[tau]};
            #pragma unroll
            for (int kt = 0; kt < 4; ++kt)
                #pragma unroll
                for (int tau = 0; tau < 4; ++tau)
                    C1[tau] = __builtin_amdgcn_mfma_f32_16x16x32_f16(a1f[kt], B1f[kt][tau], C1[tau], 0, 0, 0);
            #pragma unroll
            for (int r = 0; r < 4; ++r) {
                const float ig = fast_sigmoid(C1[0][r]);
                const float fg = fast_sigmoid(C1[1][r]);
                const float gg = fast_tanh   (C1[2][r]);
                const float og = fast_sigmoid(C1[3][r]);
                const float c  = fg * c1s[r] + ig * gg;
                c1s[r] = c;
                nxt1[(quad * 4 + r) * A1S + 64 + jcol] = (_Float16)(og * fast_tanh(c));
            }
        } else {
            const _Float16* cur0 = &A0buf[p][0];
            _Float16* nxt0 = &A0buf[1 - p][0];
            _Float16* nxt1 = &A1buf[1 - p][0];
            half8 a0f[3];
            #pragma unroll
            for (int kt = 0; kt < 3; ++kt)
                a0f[kt] = *(const half8*)&cur0[m * A0S + kt * 32 + quad * 8];
            float4v C0[4];
            #pragma unroll
            for (int tau = 0; tau < 4; ++tau)
                C0[tau] = (float4v){b0v[tau], b0v[tau], b0v[tau], b0v[tau]};
            #pragma unroll
            for (int kt = 0; kt < 3; ++kt)
                #pragma unroll
                for (int tau = 0; tau < 4; ++tau)
                    C0[tau] = __builtin_amdgcn_mfma_f32_16x16x32_f16(a0f[kt], B0f[kt][tau], C0[tau], 0, 0, 0);
            #pragma unroll
            for (int r = 0; r < 4; ++r) {
                const float ig = fast_sigmoid(C0[0][r]);
                const float fg = fast_sigmoid(C0[1][r]);
                const float gg = fast_tanh   (C0[2][r]);
                const float og = fast_sigmoid(C0[3][r]);
                const float c  = fg * c0s[r] + ig * gg;
                c0s[r] = c;
                const _Float16 hh = (_Float16)(og * fast_tanh(c));
                const int row = quad * 4 + r;
                nxt1[row * A1S + jcol]     = hh;
                nxt0[row * A0S + 4 + jcol] = hh;
            }
            if (w4 == 2 && lane < 16) {        // x(t+2) -> nxt0 x-slot
                int tn = t + 2; if (tn > T_ENC - 1) tn = T_ENC - 1;
                *(half4_t*)&nxt0[lane * A0S] = *(const half4_t*)&xAll[(lane * T_ENC + tn) * D_IN];
            }
        }
        __syncthreads();
    }

    // ---- AR weights: grp1 swaps B0f -> B0ar = [Whh0 | Wih0@Wfc], Bfc on wave 4 ----
    half8 B0ar[4][4];
    half8 Bfc[2];
    float bfcv = 0.f;
    if (grp == 1) {
        #pragma unroll
        for (int tau = 0; tau < 4; ++tau) {
            const int n = 16 * (w4 + 4 * tau) + n16;
            #pragma unroll
            for (int kt = 0; kt < 4; ++kt)
                #pragma unroll
                for (int j = 0; j < 8; ++j) {
                    const int k = kt * 32 + quad * 8 + j;
                    float v;
                    if (k < H) v = Whh0[n * H + k];
                    else {
                        const int c = k - H;
                        v = Wih0[n * D_IN + 0] * Wfc[0 * H + c] + Wih0[n * D_IN + 1] * Wfc[1 * H + c]
                          + Wih0[n * D_IN + 2] * Wfc[2 * H + c] + Wih0[n * D_IN + 3] * Wfc[3 * H + c];
                    }
                    B0ar[kt][tau][j] = (_Float16)v;
                }
        }
        if (w4 == 0) {
            #pragma unroll
            for (int kt = 0; kt < 2; ++kt)
                #pragma unroll
                for (int j = 0; j < 8; ++j) {
                    const int k = kt * 32 + quad * 8 + j;
                    Bfc[kt][j] = (_Float16)((n16 < 4) ? Wfc[n16 * H + k] : 0.f);
                }
            if (n16 < 4) bfcv = bfc[n16];
        }
    }
    // grp0 overlaps: C1pre(0) = b1 + Whh1 · h1(127)
    float4v C1pre[4];
    if (grp == 0) {
        half8 ah[2];
        #pragma unroll
        for (int kt = 0; kt < 2; ++kt)
            ah[kt] = *(const half8*)&A1buf[0][m * A1S + 64 + kt * 32 + quad * 8];
        #pragma unroll
        for (int tau = 0; tau < 4; ++tau)
            C1pre[tau] = (float4v){b1v[tau], b1v[tau], b1v[tau], b1v[tau]};
        #pragma unroll
        for (int kt = 0; kt < 2; ++kt)
            #pragma unroll
            for (int tau = 0; tau < 4; ++tau)
                C1pre[tau] = __builtin_amdgcn_mfma_f32_16x16x32_f16(ah[kt], B1f[2 + kt][tau], C1pre[tau], 0, 0, 0);
    }

    // ---- AR: phase1 = L1 finish (grp0) || Whh0-pre (grp1); B1;
    //          phase2 = L0ar finish + head (grp1) || Whh1-pre (grp0); B2 ----
    for (int s = 0; s < STEPS; ++s) {
        const int q = s & 1;
        const _Float16* cur = &A1buf[q][0];
        _Float16* nxt = &A1buf[1 - q][0];

        half8 ah0[2];   // h0(s)
        #pragma unroll
        for (int kt = 0; kt < 2; ++kt)
            ah0[kt] = *(const half8*)&cur[m * A1S + kt * 32 + quad * 8];

        float4v C0pre[4];
        if (grp == 0) {
            float4v C1[4] = {C1pre[0], C1pre[1], C1pre[2], C1pre[3]};
            #pragma unroll
            for (int kt = 0; kt < 2; ++kt)
                #pragma unroll
                for (int tau = 0; tau < 4; ++tau)
                    C1[tau] = __builtin_amdgcn_mfma_f32_16x16x32_f16(ah0[kt], B1f[kt][tau], C1[tau], 0, 0, 0);
            #pragma unroll
            for (int r = 0; r < 4; ++r) {
                const float ig = fast_sigmoid(C1[0][r]);
                const float fg = fast_sigmoid(C1[1][r]);
                const float gg = fast_tanh   (C1[2][r]);
                const float og = fast_sigmoid(C1[3][r]);
                const float c  = fg * c1s[r] + ig * gg;
                c1s[r] = c;
                nxt[(quad * 4 + r) * A1S + 64 + jcol] = (_Float16)(og * fast_tanh(c));
            }
        } else {
            #pragma unroll
            for (int tau = 0; tau < 4; ++tau)
                C0pre[tau] = (float4v){b0arv[tau], b0arv[tau], b0arv[tau], b0arv[tau]};
            #pragma unroll
            for (int kt = 0; kt < 2; ++kt)
                #pragma unroll
                for (int tau = 0; tau < 4; ++tau)
                    C0pre[tau] = __builtin_amdgcn_mfma_f32_16x16x32_f16(ah0[kt], B0ar[kt][tau], C0pre[tau], 0, 0, 0);
        }
        __syncthreads();   // B1: h1(s) visible

        half8 ah1[2];   // h1(s)
        #pragma unroll
        for (int kt = 0; kt < 2; ++kt)
            ah1[kt] = *(const half8*)&nxt[m * A1S + 64 + kt * 32 + quad * 8];

        if (grp == 1) {
            float4v C0[4] = {C0pre[0], C0pre[1], C0pre[2], C0pre[3]};
            #pragma unroll
            for (int kt = 0; kt < 2; ++kt)
                #pragma unroll
                for (int tau = 0; tau < 4; ++tau)
                    C0[tau] = __builtin_amdgcn_mfma_f32_16x16x32_f16(ah1[kt], B0ar[2 + kt][tau], C0[tau], 0, 0, 0);
            if (w4 == 0) {   // head: pred(s) = Wfc·h1(s)+bfc, off critical path
                float4v Cp = (float4v){bfcv, bfcv, bfcv, bfcv};
                Cp = __builtin_amdgcn_mfma_f32_16x16x32_f16(ah1[0], Bfc[0], Cp, 0, 0, 0);
                Cp = __builtin_amdgcn_mfma_f32_16x16x32_f16(ah1[1], Bfc[1], Cp, 0, 0, 0);
                if (n16 < 4) {
                    #pragma unroll
                    for (int r = 0; r < 4; ++r)
                        predsS[(quad * 4 + r) * (STEPS * D_IN) + s * D_IN + n16] = Cp[r];
                }
            }
            #pragma unroll
            for (int r = 0; r < 4; ++r) {
                const float ig = fast_sigmoid(C0[0][r]);
                const float fg = fast_sigmoid(C0[1][r]);
                const float gg = fast_tanh   (C0[2][r]);
                const float og = fast_sigmoid(C0[3][r]);
                const float c  = fg * c0s[r] + ig * gg;
                c0s[r] = c;
                nxt[(quad * 4 + r) * A1S + jcol] = (_Float16)(og * fast_tanh(c));
            }
        } else {   // grp0 pre-computes C1pre(s+1) = b1 + Whh1·h1(s)
            #pragma unroll
            for (int tau = 0; tau < 4; ++tau)
                C1pre[tau] = (float4v){b1v[tau], b1v[tau], b1v[tau], b1v[tau]};
            #pragma unroll
            for (int kt = 0; kt < 2; ++kt)
                #pragma unroll
                for (int tau = 0; tau < 4; ++tau)
                    C1pre[tau] = __builtin_amdgcn_mfma_f32_16x16x32_f16(ah1[kt], B1f[2 + kt][tau], C1pre[tau], 0, 0, 0);
        }
        __syncthreads();   // B2: h0(s+1) visible
    }

    // ---- bulk store preds ----
    for (int j = tid; j < M * STEPS; j += 512) {
        const int elem = j / STEPS, r = j - elem * STEPS;
        ((float4v*)out)[(size_t)(m0 + elem) * STEPS + r] = ((const float4v*)predsS)[j];
    }
}

extern "C" void kernel_launch(void* const* d_in, const int* in_sizes, int n_in,
                              void* d_out, int out_size, void* d_ws, size_t ws_size,
                              hipStream_t stream) {
    const float* x    = (const float*)d_in[0];
    const float* Wih0 = (const float*)d_in[1];
    const float* Whh0 = (const float*)d_in[2];
    const float* bih0 = (const float*)d_in[3];
    const float* bhh0 = (const float*)d_in[4];
    const float* Wih1 = (const float*)d_in[5];
    const float* Whh1 = (const float*)d_in[6];
    const float* bih1 = (const float*)d_in[7];
    const float* bhh1 = (const float*)d_in[8];
    const float* Wfc  = (const float*)d_in[9];
    const float* bfc  = (const float*)d_in[10];
    float* out = (float*)d_out;

    dim3 grid(4096 / M);   // 256 blocks, one per CU
    dim3 block(512);       // 8 waves = 2 per SIMD (grp0 wave + grp1 wave per SIMD)
    lstm_ar_kernel<<<grid, block, 0, stream>>>(
        x, Wih0, Whh0, bih0, bhh0, Wih1, Whh1, bih1, bhh1, Wfc, bfc, out);
}